// Round 7
// baseline (252.208 us; speedup 1.0000x reference)
//
#include <hip/hip_runtime.h>
#include <cstdint>
#include <cstddef>

// ---------------------------------------------------------------------------
// GCN: 3 layers, shared graph.
//   - Graph preprocessing once: degree, D^-1/2, CSR-by-dst, hierarchical scan.
//   - Features between stages packed bf16x2 (halves gather bytes).
//   - Agg: half-wave edge-pairing — lanes 0-31 take even edges, 32-63 odd,
//     4 dims (uint2) per lane, so ONE gather instruction serves TWO edges.
//     Halves per-edge VMEM + address VALU (R6: 57% VALUBusy, issue-bound).
//     4-pair unroll = 8 edges in flight; shfl_xor(32) merges halves at end.
//   - GEMMs: bf16 MFMA 16x16x32 (f32 accum), W pre-transposed bf16,
//     A staged in padded LDS (stride 136), C/D: col=lane&15, row=(lane>>4)*4+reg.
//   - Layer 3 via linearity + fused projection/log_softmax (butterfly).
// ---------------------------------------------------------------------------

typedef unsigned int uint;
typedef unsigned short u16;
typedef uint  uint4e  __attribute__((ext_vector_type(4)));
typedef float float4e __attribute__((ext_vector_type(4)));
typedef uint  uint2e  __attribute__((ext_vector_type(2)));
typedef int   int2e   __attribute__((ext_vector_type(2)));
using bf16x8 = __attribute__((ext_vector_type(8))) short;
using f32x4  = __attribute__((ext_vector_type(4))) float;

__device__ __forceinline__ float bf_lo(uint v) { return __uint_as_float(v << 16); }
__device__ __forceinline__ float bf_hi(uint v) { return __uint_as_float(v & 0xffff0000u); }
__device__ __forceinline__ u16 bf16_1(float a) {
    uint ua = __float_as_uint(a);
    ua = (ua + 0x7fffu + ((ua >> 16) & 1u)) >> 16;          // RNE
    return (u16)ua;
}
__device__ __forceinline__ uint pack_bf2(float a, float b) {
    return (uint)bf16_1(a) | ((uint)bf16_1(b) << 16);
}

__global__ void count_kernel(const int* __restrict__ ei, int E, int* __restrict__ cnt) {
    int i = blockIdx.x * blockDim.x + threadIdx.x;
    int stride = gridDim.x * blockDim.x;
    for (int e = i; e < E; e += stride) atomicAdd(&cnt[ei[E + e]], 1);
}

// Pass 1: per-block (1024 elems) totals; also computes dis = rsqrt(deg+1).
__global__ __launch_bounds__(256) void scan_partial(const int* __restrict__ cnt,
        int* __restrict__ bsum, float* __restrict__ dis, int n) {
    __shared__ int red[256];
    int b = blockIdx.x, tid = threadIdx.x;
    int base = b * 1024 + tid * 4;
    int4 v = make_int4(0, 0, 0, 0);
    if (base + 4 <= n) {
        v = *reinterpret_cast<const int4*>(cnt + base);
    } else {
        if (base + 0 < n) v.x = cnt[base + 0];
        if (base + 1 < n) v.y = cnt[base + 1];
        if (base + 2 < n) v.z = cnt[base + 2];
    }
    if (base + 0 < n) dis[base + 0] = rsqrtf((float)(v.x + 1));
    if (base + 1 < n) dis[base + 1] = rsqrtf((float)(v.y + 1));
    if (base + 2 < n) dis[base + 2] = rsqrtf((float)(v.z + 1));
    if (base + 3 < n) dis[base + 3] = rsqrtf((float)(v.w + 1));
    red[tid] = v.x + v.y + v.z + v.w;
    __syncthreads();
    for (int d = 128; d > 0; d >>= 1) {
        if (tid < d) red[tid] += red[tid + d];
        __syncthreads();
    }
    if (tid == 0) bsum[b] = red[0];
}

// Pass 2: wave 0 redundantly scans block sums for this block's offset, then
// block-local exclusive scan + offset -> row_ptr.
__global__ __launch_bounds__(256) void scan_final(const int* __restrict__ cnt,
        const int* __restrict__ bsum, int* __restrict__ row_ptr, int nb, int n) {
    __shared__ int red[256];
    __shared__ int sh_boff;
    int b = blockIdx.x, tid = threadIdx.x;
    if (tid < 64) {
        int s = (tid < nb) ? bsum[tid] : 0;
        int v = s;
        for (int d = 1; d < 64; d <<= 1) {
            int t = __shfl_up(v, d);
            if (tid >= d) v += t;
        }
        if (tid == b) sh_boff = v - s;                 // exclusive offset of this block
        if (b == 0 && tid == 63) row_ptr[n] = v;       // grand total
    }
    int base = b * 1024 + tid * 4;
    int4 v = make_int4(0, 0, 0, 0);
    if (base + 4 <= n) {
        v = *reinterpret_cast<const int4*>(cnt + base);
    } else {
        if (base + 0 < n) v.x = cnt[base + 0];
        if (base + 1 < n) v.y = cnt[base + 1];
        if (base + 2 < n) v.z = cnt[base + 2];
    }
    int s = v.x + v.y + v.z + v.w;
    red[tid] = s;
    __syncthreads();
    for (int d = 1; d < 256; d <<= 1) {
        int t = (tid >= d) ? red[tid - d] : 0;
        __syncthreads();
        red[tid] += t;
        __syncthreads();
    }
    int off = sh_boff + red[tid] - s;
    if (base + 0 < n) { row_ptr[base + 0] = off; off += v.x; }
    if (base + 1 < n) { row_ptr[base + 1] = off; off += v.y; }
    if (base + 2 < n) { row_ptr[base + 2] = off; off += v.z; }
    if (base + 3 < n) { row_ptr[base + 3] = off; }
}

__global__ void fill_kernel(const int* __restrict__ ei, int E,
                            const int* __restrict__ row_ptr, int* __restrict__ fillc,
                            const float* __restrict__ dis, int2e* __restrict__ esort) {
    int i = blockIdx.x * blockDim.x + threadIdx.x;
    int stride = gridDim.x * blockDim.x;
    for (int e = i; e < E; e += stride) {
        int s = ei[e];
        int d = ei[E + e];
        int pos = row_ptr[d] + atomicAdd(&fillc[d], 1);
        float nm = dis[s] * dis[d];
        int2e pkt;
        pkt.x = s;
        pkt.y = __float_as_int(nm);
        esort[pos] = pkt;
    }
}

// One-time: Wt[c][k] = bf16(W[k][c]) for both weight matrices (blockIdx picks).
__global__ __launch_bounds__(256) void wt_kernel(const float* __restrict__ Wa,
        const float* __restrict__ Wb, u16* __restrict__ Wta, u16* __restrict__ Wtb) {
    const float* W = blockIdx.x ? Wb : Wa;
    u16* Wt = blockIdx.x ? Wtb : Wta;
    int tid = threadIdx.x;
    for (int i = 0; i < 64; ++i) {
        int idx = tid + i * 256;          // 16384 = 128*128
        int k = idx >> 7, c = idx & 127;
        Wt[c * 128 + k] = bf16_1(W[idx]); // read coalesced, write scattered (once)
    }
}

// out u16[n][128] = bf16( A[n][128] @ W ),  W given as Wt bf16 [col][k].
template <typename TA>
__global__ __launch_bounds__(256) void gemm_mfma(const TA* __restrict__ A,
        const u16* __restrict__ Wt, u16* __restrict__ out, int n) {
    constexpr int LDA = 136;                 // 128 + 8 pad (bf16) -> 2-way LDS only
    __shared__ u16 as[64 * LDA];
    int tid = threadIdx.x;
    int wave = tid >> 6, lane = tid & 63;
    int row0 = blockIdx.x * 64;
    int l16 = lane & 15;
    int krow = (lane >> 4) * 8;              // k-octet within 32-wide K block

    if constexpr (sizeof(TA) == 4) {
#pragma unroll
        for (int i = 0; i < 8; ++i) {
            int idx = tid + i * 256;         // 2048 quads of 4 f32
            int r = idx >> 5;
            int q = (idx & 31) * 4;
            float4e v = {0.f, 0.f, 0.f, 0.f};
            if (row0 + r < n)
                v = *reinterpret_cast<const float4e*>((const float*)A + (size_t)(row0 + r) * 128 + q);
            uint2e p;
            p.x = pack_bf2(v.x, v.y);
            p.y = pack_bf2(v.z, v.w);
            *reinterpret_cast<uint2e*>(&as[r * LDA + q]) = p;
        }
    } else {
#pragma unroll
        for (int i = 0; i < 4; ++i) {
            int idx = tid + i * 256;         // 1024 octs of 8 bf16
            int r = idx >> 4;
            int q = (idx & 15) * 8;
            uint4e v = {0u, 0u, 0u, 0u};
            if (row0 + r < n)
                v = *reinterpret_cast<const uint4e*>((const u16*)A + (size_t)(row0 + r) * 128 + q);
            *reinterpret_cast<uint4e*>(&as[r * LDA + q]) = v;
        }
    }

    bf16x8 b[2][4];
#pragma unroll
    for (int n2 = 0; n2 < 2; ++n2)
#pragma unroll
        for (int kb = 0; kb < 4; ++kb)
            b[n2][kb] = *reinterpret_cast<const bf16x8*>(
                Wt + (size_t)(wave * 32 + n2 * 16 + l16) * 128 + kb * 32 + krow);

    __syncthreads();

    f32x4 acc[4][2] = {};
#pragma unroll
    for (int m = 0; m < 4; ++m) {
#pragma unroll
        for (int kb = 0; kb < 4; ++kb) {
            bf16x8 a = *reinterpret_cast<const bf16x8*>(
                &as[(m * 16 + l16) * LDA + kb * 32 + krow]);
#pragma unroll
            for (int n2 = 0; n2 < 2; ++n2)
                acc[m][n2] = __builtin_amdgcn_mfma_f32_16x16x32_bf16(a, b[n2][kb], acc[m][n2], 0, 0, 0);
        }
    }

#pragma unroll
    for (int m = 0; m < 4; ++m) {
        int rbase = row0 + m * 16 + (lane >> 4) * 4;
#pragma unroll
        for (int n2 = 0; n2 < 2; ++n2) {
            int col = wave * 32 + n2 * 16 + l16;
#pragma unroll
            for (int r = 0; r < 4; ++r) {
                int row = rbase + r;
                if (row < n) out[(size_t)row * 128 + col] = bf16_1(acc[m][n2][r]);
            }
        }
    }
}

// Half-wave paired gather: lanes 0-31 even edges, 32-63 odd edges; 4 dims/lane.
// On return, ALL lanes hold combined a0..a3 = node dims [4j .. 4j+3], j=lane&31.
__device__ __forceinline__ void gather_accum2(const uint* __restrict__ xw,
        const int2e* __restrict__ esort, const float* __restrict__ dis,
        int v, int half, int j, int beg, int end,
        float& a0, float& a1, float& a2, float& a3) {
    int e = beg;
    for (; e + 7 < end; e += 8) {                       // 8 edges, 4 gathers in flight
        int2e ed[4];
        uint2e r[4];
#pragma unroll
        for (int p = 0; p < 4; ++p) ed[p] = esort[e + 2 * p + half];
#pragma unroll
        for (int p = 0; p < 4; ++p)
            r[p] = *reinterpret_cast<const uint2e*>(xw + (size_t)ed[p].x * 64 + j * 2);
#pragma unroll
        for (int p = 0; p < 4; ++p) {
            float w = __int_as_float(ed[p].y);
            a0 += w * bf_lo(r[p].x); a1 += w * bf_hi(r[p].x);
            a2 += w * bf_lo(r[p].y); a3 += w * bf_hi(r[p].y);
        }
    }
    for (; e + 1 < end; e += 2) {                       // pair tail
        int2e ed = esort[e + half];
        uint2e r = *reinterpret_cast<const uint2e*>(xw + (size_t)ed.x * 64 + j * 2);
        float w = __int_as_float(ed.y);
        a0 += w * bf_lo(r.x); a1 += w * bf_hi(r.x);
        a2 += w * bf_lo(r.y); a3 += w * bf_hi(r.y);
    }
    if (e < end) {                                      // odd single: half 0 only
        int2e ed = esort[e];
        uint2e r = *reinterpret_cast<const uint2e*>(xw + (size_t)ed.x * 64 + j * 2);
        float w = half ? 0.f : __int_as_float(ed.y);
        a0 += w * bf_lo(r.x); a1 += w * bf_hi(r.x);
        a2 += w * bf_lo(r.y); a3 += w * bf_hi(r.y);
    }
    {                                                   // self-loop: half 0 only
        float dv = dis[v];
        float wv = half ? 0.f : dv * dv;
        uint2e r = *reinterpret_cast<const uint2e*>(xw + (size_t)v * 64 + j * 2);
        a0 += wv * bf_lo(r.x); a1 += wv * bf_hi(r.x);
        a2 += wv * bf_lo(r.y); a3 += wv * bf_hi(r.y);
    }
    a0 += __shfl_xor(a0, 32);                           // merge halves (symmetric)
    a1 += __shfl_xor(a1, 32);
    a2 += __shfl_xor(a2, 32);
    a3 += __shfl_xor(a3, 32);
}

// CSR aggregation -> packed bf16. MODE: 1 = +bias, 2 = +bias+relu.
template <int MODE>
__global__ __launch_bounds__(256) void agg_kernel(const uint* __restrict__ xw,
        const int* __restrict__ row_ptr, const int2e* __restrict__ esort,
        const float* __restrict__ dis, const float* __restrict__ bias,
        uint* __restrict__ out, int n) {
    int v = (int)((blockIdx.x * blockDim.x + threadIdx.x) >> 6);
    int lane = threadIdx.x & 63;
    if (v >= n) return;
    int half = lane >> 5, j = lane & 31;
    float a0 = 0.f, a1 = 0.f, a2 = 0.f, a3 = 0.f;
    gather_accum2(xw, esort, dis, v, half, j, row_ptr[v], row_ptr[v + 1], a0, a1, a2, a3);
    float4e bv = *reinterpret_cast<const float4e*>(bias + j * 4);
    a0 += bv.x; a1 += bv.y; a2 += bv.z; a3 += bv.w;
    if (MODE == 2) {
        a0 = fmaxf(a0, 0.f); a1 = fmaxf(a1, 0.f);
        a2 = fmaxf(a2, 0.f); a3 = fmaxf(a3, 0.f);
    }
    if (!half) {
        uint2e o = {pack_bf2(a0, a1), pack_bf2(a2, a3)};
        *reinterpret_cast<uint2e*>(out + (size_t)v * 64 + j * 2) = o;
    }
}

// Final layer fused: h = Agg(h2); out = log_softmax(h @ W3 + b3).
// Lane (half,j) holds dims 4j..4j+3; projection splits W3 rows across halves.
__global__ __launch_bounds__(256) void agg_out_kernel(const uint* __restrict__ xw,
        const int* __restrict__ row_ptr, const int2e* __restrict__ esort,
        const float* __restrict__ dis, const float* __restrict__ W3,
        const float* __restrict__ b3, float* __restrict__ out, int n) {
    int v = (int)((blockIdx.x * blockDim.x + threadIdx.x) >> 6);
    int lane = threadIdx.x & 63;
    if (v >= n) return;
    int half = lane >> 5, j = lane & 31;
    float a0 = 0.f, a1 = 0.f, a2 = 0.f, a3 = 0.f;
    gather_accum2(xw, esort, dis, v, half, j, row_ptr[v], row_ptr[v + 1], a0, a1, a2, a3);
    // lane covers W3 rows (4j + 2*half, 4j + 2*half + 1)
    const float* w0 = W3 + (size_t)(j * 4 + half * 2) * 10;
    float hA = half ? a2 : a0;
    float hB = half ? a3 : a1;
    float p[10];
#pragma unroll
    for (int c = 0; c < 10; ++c) p[c] = hA * w0[c] + hB * w0[10 + c];
#pragma unroll
    for (int c = 0; c < 10; ++c) {
#pragma unroll
        for (int d = 1; d < 64; d <<= 1) p[c] += __shfl_xor(p[c], d);
    }
#pragma unroll
    for (int c = 0; c < 10; ++c) p[c] += b3[c];
    float m = p[0];
#pragma unroll
    for (int c = 1; c < 10; ++c) m = fmaxf(m, p[c]);
    float ssum = 0.f;
#pragma unroll
    for (int c = 0; c < 10; ++c) ssum += __expf(p[c] - m);
    float ls = __logf(ssum);
    if (lane < 10) out[(size_t)v * 10 + lane] = p[lane] - m - ls;
}

extern "C" void kernel_launch(void* const* d_in, const int* in_sizes, int n_in,
                              void* d_out, int out_size, void* d_ws, size_t ws_size,
                              hipStream_t stream) {
    const float* x  = (const float*)d_in[0];
    const int*   ei = (const int*)d_in[1];   // [2][E] int32
    const float* W1 = (const float*)d_in[2];
    const float* b1 = (const float*)d_in[3];
    const float* W2 = (const float*)d_in[4];
    const float* b2 = (const float*)d_in[5];
    const float* W3 = (const float*)d_in[6];
    const float* b3 = (const float*)d_in[7];
    int N = in_sizes[0] / 128;
    int E = in_sizes[1] / 2;
    int NB = (N + 1023) / 1024;   // 49 for N=50000 (must be <= 64)

    char* ws = (char*)d_ws;
    size_t off = 0;
    auto alloc = [&](size_t bytes) -> char* {
        char* p = ws + off;
        off = (off + bytes + 255) & ~(size_t)255;
        return p;
    };
    int*   cnt     = (int*)alloc((size_t)N * 4);
    int*   fillc   = (int*)alloc((size_t)N * 4);
    int*   row_ptr = (int*)alloc(((size_t)N + 1) * 4);
    float* dis     = (float*)alloc((size_t)N * 4);
    int*   bsum    = (int*)alloc(64 * 4);
    u16*   Wt1     = (u16*)alloc(128 * 128 * 2);
    u16*   Wt2     = (u16*)alloc(128 * 128 * 2);
    int2e* esort   = (int2e*)alloc((size_t)E * 8);
    uint*  bufA    = (uint*)alloc((size_t)N * 64 * 4);   // bf16x2 packed [N][64]
    uint*  bufB    = (uint*)alloc((size_t)N * 64 * 4);   // bf16x2 packed [N][64]

    // cnt and fillc are adjacent in ws: one memset covers both.
    (void)hipMemsetAsync(cnt, 0, (size_t)((char*)fillc - (char*)cnt) + (size_t)N * 4, stream);

    // --- graph preprocessing (shared by all 3 layers) + weight transposes ---
    count_kernel<<<2048, 256, 0, stream>>>(ei, E, cnt);
    wt_kernel<<<2, 256, 0, stream>>>(W1, W2, Wt1, Wt2);
    scan_partial<<<NB, 256, 0, stream>>>(cnt, bsum, dis, N);
    scan_final<<<NB, 256, 0, stream>>>(cnt, bsum, row_ptr, NB, N);
    fill_kernel<<<2048, 256, 0, stream>>>(ei, E, row_ptr, fillc, dis, esort);

    int gemm_grid = (N + 63) / 64;
    // --- layer 1: relu(Agg(x@W1) + b1) ---
    gemm_mfma<float><<<gemm_grid, 256, 0, stream>>>(x, Wt1, (u16*)bufA, N);
    agg_kernel<2><<<(N + 3) / 4, 256, 0, stream>>>(bufA, row_ptr, esort, dis, b1, bufB, N);
    // --- layer 2: Agg(h1@W2) + b2 ---
    gemm_mfma<u16><<<gemm_grid, 256, 0, stream>>>((const u16*)bufB, Wt2, (u16*)bufA, N);
    agg_kernel<1><<<(N + 3) / 4, 256, 0, stream>>>(bufA, row_ptr, esort, dis, b2, bufB, N);
    // --- layer 3 fused: log_softmax(Agg(h2) @ W3 + b3) ---
    agg_out_kernel<<<(N + 3) / 4, 256, 0, stream>>>(bufB, row_ptr, esort, dis, W3, b3,
                                                    (float*)d_out, N);
}